// Round 2
// baseline (203.812 us; speedup 1.0000x reference)
//
#include <hip/hip_runtime.h>
#include <hip/hip_bf16.h>

// GCN with DropEdge: out = A_norm @ (relu(A_norm @ (X@W0)) @ W1)
// A_norm = D^-1/2 (mask.A + I) D^-1/2
//
// N=50000 nodes, E=600000 edges, D_IN=D_HID=128, D_OUT=64, all fp32.
// NOTE: harness canonicalizes integer/bool inputs to int32 -> edge_mask is const int*.

#define BLK 256

// ---------------- setup kernels ----------------

__global__ __launch_bounds__(BLK) void initK(float* deg, int* counts, int n) {
    int i = blockIdx.x * BLK + threadIdx.x;
    if (i < n) { deg[i] = 1.0f; counts[i] = 0; }
}

__global__ __launch_bounds__(BLK) void countK(const int* __restrict__ erow,
                                              const float* __restrict__ evals,
                                              const int* __restrict__ emask,
                                              float* deg, int* counts, int e) {
    int i = blockIdx.x * BLK + threadIdx.x;
    if (i >= e) return;
    if (!emask[i]) return;
    int r = erow[i];
    atomicAdd(&counts[r], 1);
    atomicAdd(&deg[r], evals[i]);
}

__global__ __launch_bounds__(BLK) void dinvK(float* degdis, int n) {
    int i = blockIdx.x * BLK + threadIdx.x;
    if (i < n) degdis[i] = fminf(rsqrtf(degdis[i]), 10.0f);
}

// ---------------- exclusive scan over counts -> rowptr ----------------

__global__ __launch_bounds__(BLK) void scan1K(const int* __restrict__ counts,
                                              int* __restrict__ rowptr,
                                              int* __restrict__ bsums, int n) {
    __shared__ int s[BLK];
    int t = threadIdx.x;
    int i = blockIdx.x * BLK + t;
    int v = (i < n) ? counts[i] : 0;
    s[t] = v;
    __syncthreads();
    for (int off = 1; off < BLK; off <<= 1) {
        int u = (t >= off) ? s[t - off] : 0;
        __syncthreads();
        s[t] += u;
        __syncthreads();
    }
    if (i < n) rowptr[i + 1] = s[t];           // inclusive scan, shifted
    if (t == BLK - 1) bsums[blockIdx.x] = s[t];
}

__global__ __launch_bounds__(BLK) void scan2K(int* bsums, int nb) {
    __shared__ int s[BLK];
    int t = threadIdx.x;
    int v = (t < nb) ? bsums[t] : 0;
    s[t] = v;
    __syncthreads();
    for (int off = 1; off < BLK; off <<= 1) {
        int u = (t >= off) ? s[t - off] : 0;
        __syncthreads();
        s[t] += u;
        __syncthreads();
    }
    if (t < nb) bsums[t] = s[t] - v;           // exclusive block offsets
}

__global__ __launch_bounds__(BLK) void scan3K(int* __restrict__ rowptr,
                                              const int* __restrict__ bsums,
                                              int* __restrict__ cursor, int n) {
    int t = threadIdx.x;
    int i = blockIdx.x * BLK + t;
    if (i < n) {
        int v = rowptr[i + 1] + bsums[blockIdx.x];
        rowptr[i + 1] = v;
        if (i + 1 < n) cursor[i + 1] = v;
        if (i == 0) { rowptr[0] = 0; cursor[0] = 0; }
    }
}

__global__ __launch_bounds__(BLK) void scatterK(const int* __restrict__ erow,
                                                const int* __restrict__ ecolin,
                                                const float* __restrict__ evals,
                                                const int* __restrict__ emask,
                                                const float* __restrict__ dis,
                                                int* cursor, int* __restrict__ ecol,
                                                float* __restrict__ enval, int e) {
    int i = blockIdx.x * BLK + threadIdx.x;
    if (i >= e) return;
    if (!emask[i]) return;
    int r = erow[i], c = ecolin[i];
    float nv = evals[i] * dis[r] * dis[c];
    int pos = atomicAdd(&cursor[r], 1);
    ecol[pos] = c;
    enval[pos] = nv;
}

// ---------------- dense GEMM: C[M,NC] = A[M,128] @ W[128,NC] ----------------
// W fully in LDS; 4 rows x 4 cols register blocking per thread, float4 LDS reads.

template <int NC>
__global__ __launch_bounds__(BLK) void gemmK(const float* __restrict__ A,
                                             const float* __restrict__ W,
                                             float* __restrict__ C, int M) {
    constexpr int ROWS = 4096 / NC;   // 32 (NC=128) or 64 (NC=64) rows per block
    __shared__ float ws[128 * NC];
    __shared__ float xs[ROWS * 128];
    int t = threadIdx.x;
    for (int i = t * 4; i < 128 * NC; i += BLK * 4)
        *(float4*)&ws[i] = *(const float4*)&W[i];
    int row0 = blockIdx.x * ROWS;
    for (int i = t * 4; i < ROWS * 128; i += BLK * 4) {
        int r = row0 + i / 128;
        float4 v = make_float4(0.f, 0.f, 0.f, 0.f);
        if (r < M) v = *(const float4*)&A[(size_t)r * 128 + (i & 127)];
        *(float4*)&xs[i] = v;
    }
    __syncthreads();

    constexpr int CG = NC / 4;        // col groups
    int cg = t % CG, rg = t / CG;
    int c0 = cg * 4, r0 = rg * 4;
    float acc[4][4] = {};
    for (int k = 0; k < 128; k += 4) {
        float4 wv[4], xv[4];
#pragma unroll
        for (int kk = 0; kk < 4; kk++) wv[kk] = *(float4*)&ws[(k + kk) * NC + c0];
#pragma unroll
        for (int rr = 0; rr < 4; rr++) xv[rr] = *(float4*)&xs[(r0 + rr) * 128 + k];
#pragma unroll
        for (int rr = 0; rr < 4; rr++) {
            float xk[4] = {xv[rr].x, xv[rr].y, xv[rr].z, xv[rr].w};
#pragma unroll
            for (int kk = 0; kk < 4; kk++) {
                acc[rr][0] += xk[kk] * wv[kk].x;
                acc[rr][1] += xk[kk] * wv[kk].y;
                acc[rr][2] += xk[kk] * wv[kk].z;
                acc[rr][3] += xk[kk] * wv[kk].w;
            }
        }
    }
#pragma unroll
    for (int rr = 0; rr < 4; rr++) {
        int r = row0 + r0 + rr;
        if (r < M) *(float4*)&C[(size_t)r * NC + c0] = *(float4*)&acc[rr][0];
    }
}

// ---------------- SpMM: one wave per row ----------------

// D=128: lane handles 2 dims (float2). Writes relu(result).
__global__ __launch_bounds__(BLK) void spmm1K(const float* __restrict__ XW,
                                              const int* __restrict__ rowptr,
                                              const int* __restrict__ ecol,
                                              const float* __restrict__ enval,
                                              const float* __restrict__ dis,
                                              float* __restrict__ H, int n) {
    int wid = (blockIdx.x * BLK + threadIdx.x) >> 6;
    int lane = threadIdx.x & 63;
    if (wid >= n) return;
    int r = wid;
    int d0 = lane * 2;
    float ds = dis[r];
    float2 self = *(const float2*)&XW[(size_t)r * 128 + d0];
    float2 acc;
    acc.x = ds * ds * self.x;
    acc.y = ds * ds * self.y;
    int beg = rowptr[r], end = rowptr[r + 1];
    for (int i = beg; i < end; i++) {
        int c = ecol[i];
        float nv = enval[i];
        float2 v = *(const float2*)&XW[(size_t)c * 128 + d0];
        acc.x += nv * v.x;
        acc.y += nv * v.y;
    }
    float2 o;
    o.x = fmaxf(acc.x, 0.f);
    o.y = fmaxf(acc.y, 0.f);
    *(float2*)&H[(size_t)r * 128 + d0] = o;
}

// D=64: lane handles 1 dim. No activation.
__global__ __launch_bounds__(BLK) void spmm2K(const float* __restrict__ HW,
                                              const int* __restrict__ rowptr,
                                              const int* __restrict__ ecol,
                                              const float* __restrict__ enval,
                                              const float* __restrict__ dis,
                                              float* __restrict__ out, int n) {
    int wid = (blockIdx.x * BLK + threadIdx.x) >> 6;
    int lane = threadIdx.x & 63;
    if (wid >= n) return;
    int r = wid;
    float ds = dis[r];
    float acc = ds * ds * HW[(size_t)r * 64 + lane];
    int beg = rowptr[r], end = rowptr[r + 1];
    for (int i = beg; i < end; i++) {
        int c = ecol[i];
        float nv = enval[i];
        acc += nv * HW[(size_t)c * 64 + lane];
    }
    out[(size_t)r * 64 + lane] = acc;
}

// ---------------- launch ----------------

extern "C" void kernel_launch(void* const* d_in, const int* in_sizes, int n_in,
                              void* d_out, int out_size, void* d_ws, size_t ws_size,
                              hipStream_t stream) {
    const float* x = (const float*)d_in[0];
    const int* erow = (const int*)d_in[1];
    const int* ecolin = (const int*)d_in[2];
    const float* evals = (const float*)d_in[3];
    const int* emask = (const int*)d_in[4];     // bool canonicalized to int32
    const float* W0 = (const float*)d_in[5];
    const float* W1 = (const float*)d_in[6];
    float* out = (float*)d_out;

    const int n = in_sizes[0] / 128;   // 50000
    const int e = in_sizes[1];         // 600000

    char* ws = (char*)d_ws;
    size_t off = 0;
    auto alloc = [&](size_t bytes) {
        void* p = ws + off;
        off += (bytes + 255) & ~(size_t)255;
        return p;
    };
    float* degdis = (float*)alloc((size_t)n * 4);
    int* counts = (int*)alloc((size_t)n * 4);
    int* rowptr = (int*)alloc((size_t)(n + 1) * 4);
    int* cursor = (int*)alloc((size_t)n * 4);
    int* bsums = (int*)alloc(1024 * 4);
    int* ecol = (int*)alloc((size_t)e * 4);
    float* enval = (float*)alloc((size_t)e * 4);
    float* XW = (float*)alloc((size_t)n * 128 * 4);
    float* H = (float*)alloc((size_t)n * 128 * 4);
    float* HW1 = XW;  // reuse: XW dead after spmm1

    int nbN = (n + BLK - 1) / BLK;   // 196
    int nbE = (e + BLK - 1) / BLK;   // 2344

    initK<<<nbN, BLK, 0, stream>>>(degdis, counts, n);
    countK<<<nbE, BLK, 0, stream>>>(erow, evals, emask, degdis, counts, e);
    dinvK<<<nbN, BLK, 0, stream>>>(degdis, n);
    scan1K<<<nbN, BLK, 0, stream>>>(counts, rowptr, bsums, n);
    scan2K<<<1, BLK, 0, stream>>>(bsums, nbN);
    scan3K<<<nbN, BLK, 0, stream>>>(rowptr, bsums, cursor, n);
    scatterK<<<nbE, BLK, 0, stream>>>(erow, ecolin, evals, emask, degdis,
                                      cursor, ecol, enval, e);

    gemmK<128><<<(n + 31) / 32, BLK, 0, stream>>>(x, W0, XW, n);
    spmm1K<<<(n + 3) / 4, BLK, 0, stream>>>(XW, rowptr, ecol, enval, degdis, H, n);
    gemmK<64><<<(n + 63) / 64, BLK, 0, stream>>>(H, W1, HW1, n);
    spmm2K<<<(n + 3) / 4, BLK, 0, stream>>>(HW1, rowptr, ecol, enval, degdis, out, n);
}

// Round 3
// 143.877 us; speedup vs baseline: 1.4166x; 1.4166x over previous
//
#include <hip/hip_runtime.h>
#include <hip/hip_bf16.h>

// GCN with DropEdge: out = A_norm @ (relu(A_norm @ (X@W0)) @ W1)
// A_norm = D^-1/2 (mask.A + I) D^-1/2
// N=50000, E=600000, D_IN=D_HID=128, D_OUT=64. fp32 in/out, bf16 MFMA GEMMs.

#define BLK 256

typedef __attribute__((ext_vector_type(8))) short short8v;
typedef __attribute__((ext_vector_type(8))) unsigned short ushort8v;
typedef __attribute__((ext_vector_type(4))) unsigned short ushort4v;
typedef __attribute__((ext_vector_type(4))) float float4v;

__device__ inline unsigned short f2b(float f) {
    __hip_bfloat16 h = __float2bfloat16(f);
    return *reinterpret_cast<unsigned short*>(&h);
}

// ---------------- weight transpose + bf16 convert ----------------
// W0T[c][k] = bf16(W0[k][c]) (128x128), W1T[c][k] = bf16(W1[k][c]) (64x128)
__global__ __launch_bounds__(BLK) void convK(const float* __restrict__ W0,
                                             const float* __restrict__ W1,
                                             unsigned short* __restrict__ W0T,
                                             unsigned short* __restrict__ W1T) {
    int i = blockIdx.x * BLK + threadIdx.x;
    if (i < 128 * 128) {
        int c = i >> 7, k = i & 127;
        W0T[i] = f2b(W0[k * 128 + c]);
    } else if (i < 128 * 128 + 64 * 128) {
        int j = i - 128 * 128;
        int c = j >> 7, k = j & 127;
        W1T[j] = f2b(W1[k * 64 + c]);
    }
}

// ---------------- setup kernels ----------------

__global__ __launch_bounds__(BLK) void initK(float* deg, int* counts, int n) {
    int i = blockIdx.x * BLK + threadIdx.x;
    if (i < n) { deg[i] = 1.0f; counts[i] = 0; }
}

__global__ __launch_bounds__(BLK) void countK(const int* __restrict__ erow,
                                              const float* __restrict__ evals,
                                              const int* __restrict__ emask,
                                              float* deg, int* counts, int e) {
    int i = blockIdx.x * BLK + threadIdx.x;
    if (i >= e) return;
    if (!emask[i]) return;
    int r = erow[i];
    atomicAdd(&counts[r], 1);
    atomicAdd(&deg[r], evals[i]);
}

// scan over counts (inclusive, shifted into rowptr[1..]) + fused d^-1/2
__global__ __launch_bounds__(BLK) void scan1K(const int* __restrict__ counts,
                                              int* __restrict__ rowptr,
                                              int* __restrict__ bsums,
                                              float* degdis, int n) {
    __shared__ int s[BLK];
    int t = threadIdx.x;
    int i = blockIdx.x * BLK + t;
    int v = (i < n) ? counts[i] : 0;
    s[t] = v;
    __syncthreads();
    for (int off = 1; off < BLK; off <<= 1) {
        int u = (t >= off) ? s[t - off] : 0;
        __syncthreads();
        s[t] += u;
        __syncthreads();
    }
    if (i < n) {
        rowptr[i + 1] = s[t];
        degdis[i] = fminf(rsqrtf(degdis[i]), 10.0f);
    }
    if (t == BLK - 1) bsums[blockIdx.x] = s[t];
}

__global__ __launch_bounds__(BLK) void scan2K(int* bsums, int nb) {
    __shared__ int s[BLK];
    int t = threadIdx.x;
    int v = (t < nb) ? bsums[t] : 0;
    s[t] = v;
    __syncthreads();
    for (int off = 1; off < BLK; off <<= 1) {
        int u = (t >= off) ? s[t - off] : 0;
        __syncthreads();
        s[t] += u;
        __syncthreads();
    }
    if (t < nb) bsums[t] = s[t] - v;           // exclusive block offsets
}

__global__ __launch_bounds__(BLK) void scan3K(int* __restrict__ rowptr,
                                              const int* __restrict__ bsums,
                                              int* __restrict__ cursor, int n) {
    int t = threadIdx.x;
    int i = blockIdx.x * BLK + t;
    if (i < n) {
        int v = rowptr[i + 1] + bsums[blockIdx.x];
        rowptr[i + 1] = v;
        if (i + 1 < n) cursor[i + 1] = v;
        if (i == 0) { rowptr[0] = 0; cursor[0] = 0; }
    }
}

__global__ __launch_bounds__(BLK) void scatterK(const int* __restrict__ erow,
                                                const int* __restrict__ ecolin,
                                                const float* __restrict__ evals,
                                                const int* __restrict__ emask,
                                                const float* __restrict__ dis,
                                                int* cursor, int* __restrict__ ecol,
                                                float* __restrict__ enval, int e) {
    int i = blockIdx.x * BLK + threadIdx.x;
    if (i >= e) return;
    if (!emask[i]) return;
    int r = erow[i], c = ecolin[i];
    float nv = evals[i] * dis[r] * dis[c];
    int pos = atomicAdd(&cursor[r], 1);
    ecol[pos] = c;
    enval[pos] = nv;
}

// ---------------- MFMA GEMM: C[M,NC] = A[M,128] @ W[128,NC] ----------------
// WT = W^T in bf16 (global, [NC][128]). A fp32 (converted in staging) or bf16.
// Block: 256 thr = 4 waves, 64 rows. Wave w: rows w*16..+16, all NC cols.
// LDS XOR swizzle (short-units: idx ^ ((row&7)<<3)) -> 2-way banks on b128 reads.

template <int NC, bool ABF16>
__global__ __launch_bounds__(BLK) void mgemmK(const void* __restrict__ Ap,
                                              const unsigned short* __restrict__ WT,
                                              float* __restrict__ C, int M) {
    constexpr int NT = NC / 16;
    __shared__ __align__(16) unsigned short sA[64 * 128];
    __shared__ __align__(16) unsigned short sB[NC * 128];
    int t = threadIdx.x;
    int row0 = blockIdx.x * 64;

    // stage B: WT[NC][128] -> sB swizzled (16B chunks)
    for (int ch = t; ch < NC * 16; ch += BLK) {
        int row = ch >> 4, c16 = ch & 15;
        int dst = row * 128 + ((c16 * 8) ^ ((row & 7) << 3));
        *(ushort8v*)&sB[dst] = *(const ushort8v*)&WT[row * 128 + c16 * 8];
    }
    // stage A
    if (ABF16) {
        const unsigned short* A = (const unsigned short*)Ap;
        for (int ch = t; ch < 64 * 16; ch += BLK) {
            int row = ch >> 4, c16 = ch & 15;
            int rg = row0 + row;
            ushort8v v = {0, 0, 0, 0, 0, 0, 0, 0};
            if (rg < M) v = *(const ushort8v*)&A[(size_t)rg * 128 + c16 * 8];
            int dst = row * 128 + ((c16 * 8) ^ ((row & 7) << 3));
            *(ushort8v*)&sA[dst] = v;
        }
    } else {
        const float* A = (const float*)Ap;
        for (int q = t; q < 64 * 32; q += BLK) {
            int row = q >> 5, c4 = q & 31;
            int rg = row0 + row;
            float4 v = make_float4(0.f, 0.f, 0.f, 0.f);
            if (rg < M) v = *(const float4*)&A[(size_t)rg * 128 + c4 * 4];
            ushort4v b = {f2b(v.x), f2b(v.y), f2b(v.z), f2b(v.w)};
            int dst = row * 128 + ((c4 * 4) ^ ((row & 7) << 3));
            *(ushort4v*)&sA[dst] = b;
        }
    }
    __syncthreads();

    int w = t >> 6, l = t & 63;
    int arow = w * 16 + (l & 15);
    int kgrp = l >> 4;
    int bcol = l & 15;
    float4v acc[NT];
#pragma unroll
    for (int nt = 0; nt < NT; nt++) acc[nt] = {0.f, 0.f, 0.f, 0.f};

#pragma unroll
    for (int ks = 0; ks < 4; ks++) {
        int koff = ks * 32 + kgrp * 8;
        short8v av = *(short8v*)&sA[arow * 128 + (koff ^ ((arow & 7) << 3))];
#pragma unroll
        for (int nt = 0; nt < NT; nt++) {
            int brow = nt * 16 + bcol;
            short8v bv = *(short8v*)&sB[brow * 128 + (koff ^ ((brow & 7) << 3))];
            acc[nt] = __builtin_amdgcn_mfma_f32_16x16x32_bf16(av, bv, acc[nt], 0, 0, 0);
        }
    }
    // C/D layout: col = lane&15, row = (lane>>4)*4 + reg
    int crow0 = row0 + w * 16 + kgrp * 4;
#pragma unroll
    for (int nt = 0; nt < NT; nt++) {
#pragma unroll
        for (int j = 0; j < 4; j++) {
            int r = crow0 + j;
            if (r < M) C[(size_t)r * NC + nt * 16 + bcol] = acc[nt][j];
        }
    }
}

// ---------------- SpMM: one wave per row, 4x-unrolled gathers ----------------

// layer 1: D=128, lane = 2 dims; writes relu(result) as packed bf16.
__global__ __launch_bounds__(BLK) void spmm1K(const float* __restrict__ XW,
                                              const int* __restrict__ rowptr,
                                              const int* __restrict__ ecol,
                                              const float* __restrict__ enval,
                                              const float* __restrict__ dis,
                                              unsigned short* __restrict__ H, int n) {
    int wid = (blockIdx.x * BLK + threadIdx.x) >> 6;
    int lane = threadIdx.x & 63;
    if (wid >= n) return;
    int r = wid, d0 = lane * 2;
    float ds = dis[r];
    float2 self = *(const float2*)&XW[(size_t)r * 128 + d0];
    float ax = ds * ds * self.x, ay = ds * ds * self.y;
    int beg = rowptr[r], end = rowptr[r + 1];
    int i = beg;
    for (; i + 4 <= end; i += 4) {
        int c0 = ecol[i], c1 = ecol[i + 1], c2 = ecol[i + 2], c3 = ecol[i + 3];
        float v0 = enval[i], v1 = enval[i + 1], v2 = enval[i + 2], v3 = enval[i + 3];
        float2 g0 = *(const float2*)&XW[(size_t)c0 * 128 + d0];
        float2 g1 = *(const float2*)&XW[(size_t)c1 * 128 + d0];
        float2 g2 = *(const float2*)&XW[(size_t)c2 * 128 + d0];
        float2 g3 = *(const float2*)&XW[(size_t)c3 * 128 + d0];
        ax += v0 * g0.x + v1 * g1.x + v2 * g2.x + v3 * g3.x;
        ay += v0 * g0.y + v1 * g1.y + v2 * g2.y + v3 * g3.y;
    }
    for (; i < end; i++) {
        int c = ecol[i];
        float v = enval[i];
        float2 g = *(const float2*)&XW[(size_t)c * 128 + d0];
        ax += v * g.x;
        ay += v * g.y;
    }
    ax = fmaxf(ax, 0.f);
    ay = fmaxf(ay, 0.f);
    unsigned int packed = (unsigned)f2b(ax) | ((unsigned)f2b(ay) << 16);
    *(unsigned int*)&H[(size_t)r * 128 + d0] = packed;
}

// layer 2: D=64, lane = 1 dim; fp32 out, no activation.
__global__ __launch_bounds__(BLK) void spmm2K(const float* __restrict__ HW,
                                              const int* __restrict__ rowptr,
                                              const int* __restrict__ ecol,
                                              const float* __restrict__ enval,
                                              const float* __restrict__ dis,
                                              float* __restrict__ out, int n) {
    int wid = (blockIdx.x * BLK + threadIdx.x) >> 6;
    int lane = threadIdx.x & 63;
    if (wid >= n) return;
    int r = wid;
    float ds = dis[r];
    float acc = ds * ds * HW[(size_t)r * 64 + lane];
    int beg = rowptr[r], end = rowptr[r + 1];
    int i = beg;
    for (; i + 4 <= end; i += 4) {
        int c0 = ecol[i], c1 = ecol[i + 1], c2 = ecol[i + 2], c3 = ecol[i + 3];
        float v0 = enval[i], v1 = enval[i + 1], v2 = enval[i + 2], v3 = enval[i + 3];
        float g0 = HW[(size_t)c0 * 64 + lane];
        float g1 = HW[(size_t)c1 * 64 + lane];
        float g2 = HW[(size_t)c2 * 64 + lane];
        float g3 = HW[(size_t)c3 * 64 + lane];
        acc += v0 * g0 + v1 * g1 + v2 * g2 + v3 * g3;
    }
    for (; i < end; i++) {
        int c = ecol[i];
        acc += enval[i] * HW[(size_t)c * 64 + lane];
    }
    out[(size_t)r * 64 + lane] = acc;
}

// ---------------- launch ----------------

extern "C" void kernel_launch(void* const* d_in, const int* in_sizes, int n_in,
                              void* d_out, int out_size, void* d_ws, size_t ws_size,
                              hipStream_t stream) {
    const float* x = (const float*)d_in[0];
    const int* erow = (const int*)d_in[1];
    const int* ecolin = (const int*)d_in[2];
    const float* evals = (const float*)d_in[3];
    const int* emask = (const int*)d_in[4];     // bool canonicalized to int32
    const float* W0 = (const float*)d_in[5];
    const float* W1 = (const float*)d_in[6];
    float* out = (float*)d_out;

    const int n = in_sizes[0] / 128;   // 50000
    const int e = in_sizes[1];         // 600000

    char* ws = (char*)d_ws;
    size_t off = 0;
    auto alloc = [&](size_t bytes) {
        void* p = ws + off;
        off += (bytes + 255) & ~(size_t)255;
        return p;
    };
    float* degdis = (float*)alloc((size_t)n * 4);
    int* counts = (int*)alloc((size_t)n * 4);
    int* rowptr = (int*)alloc((size_t)(n + 1) * 4);
    int* cursor = (int*)alloc((size_t)n * 4);
    int* bsums = (int*)alloc(1024 * 4);
    int* ecol = (int*)alloc((size_t)e * 4);
    float* enval = (float*)alloc((size_t)e * 4);
    unsigned short* W0T = (unsigned short*)alloc(128 * 128 * 2);
    unsigned short* W1T = (unsigned short*)alloc(64 * 128 * 2);
    float* XW = (float*)alloc((size_t)n * 128 * 4);
    unsigned short* H = (unsigned short*)alloc((size_t)n * 128 * 2);
    float* HW1 = XW;  // reuse: XW (fp32) dead after spmm1; HW1 is n*64 fp32

    int nbN = (n + BLK - 1) / BLK;   // 196
    int nbE = (e + BLK - 1) / BLK;   // 2344
    int nbG = (n + 63) / 64;         // 782 gemm blocks

    convK<<<(128 * 128 + 64 * 128 + BLK - 1) / BLK, BLK, 0, stream>>>(W0, W1, W0T, W1T);
    initK<<<nbN, BLK, 0, stream>>>(degdis, counts, n);
    countK<<<nbE, BLK, 0, stream>>>(erow, evals, emask, degdis, counts, e);
    scan1K<<<nbN, BLK, 0, stream>>>(counts, rowptr, bsums, degdis, n);
    scan2K<<<1, BLK, 0, stream>>>(bsums, nbN);
    scan3K<<<nbN, BLK, 0, stream>>>(rowptr, bsums, cursor, n);
    scatterK<<<nbE, BLK, 0, stream>>>(erow, ecolin, evals, emask, degdis,
                                      cursor, ecol, enval, e);

    mgemmK<128, false><<<nbG, BLK, 0, stream>>>(x, W0T, XW, n);
    spmm1K<<<(n + 3) / 4, BLK, 0, stream>>>(XW, rowptr, ecol, enval, degdis, H, n);
    mgemmK<64, true><<<nbG, BLK, 0, stream>>>(H, W1T, HW1, n);
    spmm2K<<<(n + 3) / 4, BLK, 0, stream>>>(HW1, rowptr, ecol, enval, degdis, out, n);
}

// Round 4
// 124.771 us; speedup vs baseline: 1.6335x; 1.1531x over previous
//
#include <hip/hip_runtime.h>
#include <hip/hip_bf16.h>

// GCN with DropEdge: out = A_norm @ (relu(A_norm @ (X@W0)) @ W1)
// A_norm = D^-1/2 (mask.A + I) D^-1/2
// N=50000, E=600000, D_IN=D_HID=128, D_OUT=64. fp32 in/out.
// bf16 MFMA GEMMs; all intermediate dense matrices stored bf16 to halve
// gather/write traffic (error budget: ~6e-3 vs 1.7e-2 threshold).

#define BLK 256

typedef __attribute__((ext_vector_type(8))) short short8v;
typedef __attribute__((ext_vector_type(8))) unsigned short ushort8v;
typedef __attribute__((ext_vector_type(4))) unsigned short ushort4v;
typedef __attribute__((ext_vector_type(4))) float float4v;

__device__ inline unsigned short f2b(float f) {
    __hip_bfloat16 h = __float2bfloat16(f);
    return *reinterpret_cast<unsigned short*>(&h);
}
__device__ inline float b2f(unsigned short u) {
    unsigned int v = (unsigned int)u << 16;
    return *reinterpret_cast<float*>(&v);
}

// ---------------- prep: weight transpose->bf16 + deg/count init ----------------
__global__ __launch_bounds__(BLK) void prepK(const float* __restrict__ W0,
                                             const float* __restrict__ W1,
                                             unsigned short* __restrict__ W0T,
                                             unsigned short* __restrict__ W1T,
                                             float* deg, int* counts, int n) {
    int i = blockIdx.x * BLK + threadIdx.x;
    if (i < n) { deg[i] = 1.0f; counts[i] = 0; }
    if (i < 128 * 128) {
        int c = i >> 7, k = i & 127;
        W0T[i] = f2b(W0[k * 128 + c]);
    } else if (i < 128 * 128 + 64 * 128) {
        int j = i - 128 * 128;
        int c = j >> 7, k = j & 127;
        W1T[j] = f2b(W1[k * 64 + c]);
    }
}

// count + degree + within-row rank (atomic returns old count)
__global__ __launch_bounds__(BLK) void countK(const int* __restrict__ erow,
                                              const float* __restrict__ evals,
                                              const int* __restrict__ emask,
                                              float* deg, int* counts,
                                              int* __restrict__ rankA, int e) {
    int i = blockIdx.x * BLK + threadIdx.x;
    if (i >= e) return;
    if (!emask[i]) return;
    int r = erow[i];
    int rank = atomicAdd(&counts[r], 1);
    atomicAdd(&deg[r], evals[i]);
    rankA[i] = rank;
}

// scan over counts (inclusive, shifted into rowptr[1..]) + fused d^-1/2
__global__ __launch_bounds__(BLK) void scan1K(const int* __restrict__ counts,
                                              int* __restrict__ rowptr,
                                              int* __restrict__ bsums,
                                              float* degdis, int n) {
    __shared__ int s[BLK];
    int t = threadIdx.x;
    int i = blockIdx.x * BLK + t;
    int v = (i < n) ? counts[i] : 0;
    s[t] = v;
    __syncthreads();
    for (int off = 1; off < BLK; off <<= 1) {
        int u = (t >= off) ? s[t - off] : 0;
        __syncthreads();
        s[t] += u;
        __syncthreads();
    }
    if (i < n) {
        rowptr[i + 1] = s[t];
        degdis[i] = fminf(rsqrtf(degdis[i]), 10.0f);
    }
    if (t == BLK - 1) bsums[blockIdx.x] = s[t];
}

__global__ __launch_bounds__(BLK) void scan2K(int* bsums, int nb) {
    __shared__ int s[BLK];
    int t = threadIdx.x;
    int v = (t < nb) ? bsums[t] : 0;
    s[t] = v;
    __syncthreads();
    for (int off = 1; off < BLK; off <<= 1) {
        int u = (t >= off) ? s[t - off] : 0;
        __syncthreads();
        s[t] += u;
        __syncthreads();
    }
    if (t < nb) bsums[t] = s[t] - v;           // exclusive block offsets
}

__global__ __launch_bounds__(BLK) void scan3K(int* __restrict__ rowptr,
                                              const int* __restrict__ bsums, int n) {
    int t = threadIdx.x;
    int i = blockIdx.x * BLK + t;
    if (i < n) {
        rowptr[i + 1] += bsums[blockIdx.x];
        if (i == 0) rowptr[0] = 0;
    }
}

// rank-based scatter: no atomics
__global__ __launch_bounds__(BLK) void scatterK(const int* __restrict__ erow,
                                                const int* __restrict__ ecolin,
                                                const float* __restrict__ evals,
                                                const int* __restrict__ emask,
                                                const float* __restrict__ dis,
                                                const int* __restrict__ rowptr,
                                                const int* __restrict__ rankA,
                                                int* __restrict__ ecol,
                                                float* __restrict__ enval, int e) {
    int i = blockIdx.x * BLK + threadIdx.x;
    if (i >= e) return;
    if (!emask[i]) return;
    int r = erow[i], c = ecolin[i];
    int pos = rowptr[r] + rankA[i];
    ecol[pos] = c;
    enval[pos] = evals[i] * dis[r] * dis[c];
}

// ---------------- MFMA GEMM: C[M,NC] = A[M,128] @ W[128,NC], bf16 out ----------
// WT = W^T in bf16 (global, [NC][128]). A fp32 (converted in staging) or bf16.
// Block: 256 thr = 4 waves, 64 rows. Wave w: rows w*16..+16, all NC cols.
// LDS XOR swizzle (short-units: idx ^ ((row&7)<<3)) -> 2-way banks on b128 reads.

template <int NC, bool ABF16>
__global__ __launch_bounds__(BLK) void mgemmK(const void* __restrict__ Ap,
                                              const unsigned short* __restrict__ WT,
                                              unsigned short* __restrict__ C, int M) {
    constexpr int NT = NC / 16;
    __shared__ __align__(16) unsigned short sA[64 * 128];
    __shared__ __align__(16) unsigned short sB[NC * 128];
    int t = threadIdx.x;
    int row0 = blockIdx.x * 64;

    // stage B: WT[NC][128] -> sB swizzled (16B chunks)
    for (int ch = t; ch < NC * 16; ch += BLK) {
        int row = ch >> 4, c16 = ch & 15;
        int dst = row * 128 + ((c16 * 8) ^ ((row & 7) << 3));
        *(ushort8v*)&sB[dst] = *(const ushort8v*)&WT[row * 128 + c16 * 8];
    }
    // stage A
    if (ABF16) {
        const unsigned short* A = (const unsigned short*)Ap;
        for (int ch = t; ch < 64 * 16; ch += BLK) {
            int row = ch >> 4, c16 = ch & 15;
            int rg = row0 + row;
            ushort8v v = {0, 0, 0, 0, 0, 0, 0, 0};
            if (rg < M) v = *(const ushort8v*)&A[(size_t)rg * 128 + c16 * 8];
            int dst = row * 128 + ((c16 * 8) ^ ((row & 7) << 3));
            *(ushort8v*)&sA[dst] = v;
        }
    } else {
        const float* A = (const float*)Ap;
        for (int q = t; q < 64 * 32; q += BLK) {
            int row = q >> 5, c4 = q & 31;
            int rg = row0 + row;
            float4 v = make_float4(0.f, 0.f, 0.f, 0.f);
            if (rg < M) v = *(const float4*)&A[(size_t)rg * 128 + c4 * 4];
            ushort4v b = {f2b(v.x), f2b(v.y), f2b(v.z), f2b(v.w)};
            int dst = row * 128 + ((c4 * 4) ^ ((row & 7) << 3));
            *(ushort4v*)&sA[dst] = b;
        }
    }
    __syncthreads();

    int w = t >> 6, l = t & 63;
    int arow = w * 16 + (l & 15);
    int kgrp = l >> 4;
    int bcol = l & 15;
    float4v acc[NT];
#pragma unroll
    for (int nt = 0; nt < NT; nt++) acc[nt] = {0.f, 0.f, 0.f, 0.f};

#pragma unroll
    for (int ks = 0; ks < 4; ks++) {
        int koff = ks * 32 + kgrp * 8;
        short8v av = *(short8v*)&sA[arow * 128 + (koff ^ ((arow & 7) << 3))];
#pragma unroll
        for (int nt = 0; nt < NT; nt++) {
            int brow = nt * 16 + bcol;
            short8v bv = *(short8v*)&sB[brow * 128 + (koff ^ ((brow & 7) << 3))];
            acc[nt] = __builtin_amdgcn_mfma_f32_16x16x32_bf16(av, bv, acc[nt], 0, 0, 0);
        }
    }
    // C/D layout: col = lane&15, row = (lane>>4)*4 + reg
    int crow0 = row0 + w * 16 + kgrp * 4;
#pragma unroll
    for (int nt = 0; nt < NT; nt++) {
#pragma unroll
        for (int j = 0; j < 4; j++) {
            int r = crow0 + j;
            if (r < M) C[(size_t)r * NC + nt * 16 + bcol] = f2b(acc[nt][j]);
        }
    }
}

// ---------------- SpMM: one wave per row, 4x-unrolled bf16 gathers ------------

// layer 1: D=128 bf16 in, lane = 2 dims (one dword); relu -> packed bf16 out.
__global__ __launch_bounds__(BLK) void spmm1K(const unsigned short* __restrict__ XW,
                                              const int* __restrict__ rowptr,
                                              const int* __restrict__ ecol,
                                              const float* __restrict__ enval,
                                              const float* __restrict__ dis,
                                              unsigned short* __restrict__ H, int n) {
    int wid = (blockIdx.x * BLK + threadIdx.x) >> 6;
    int lane = threadIdx.x & 63;
    if (wid >= n) return;
    int r = wid, d0 = lane * 2;
    float ds = dis[r];
    unsigned int sv = *(const unsigned int*)&XW[(size_t)r * 128 + d0];
    float ax = ds * ds * b2f((unsigned short)sv);
    float ay = ds * ds * b2f((unsigned short)(sv >> 16));
    int beg = rowptr[r], end = rowptr[r + 1];
    int i = beg;
    for (; i + 4 <= end; i += 4) {
        int c0 = ecol[i], c1 = ecol[i + 1], c2 = ecol[i + 2], c3 = ecol[i + 3];
        float v0 = enval[i], v1 = enval[i + 1], v2 = enval[i + 2], v3 = enval[i + 3];
        unsigned int g0 = *(const unsigned int*)&XW[(size_t)c0 * 128 + d0];
        unsigned int g1 = *(const unsigned int*)&XW[(size_t)c1 * 128 + d0];
        unsigned int g2 = *(const unsigned int*)&XW[(size_t)c2 * 128 + d0];
        unsigned int g3 = *(const unsigned int*)&XW[(size_t)c3 * 128 + d0];
        ax += v0 * b2f((unsigned short)g0) + v1 * b2f((unsigned short)g1)
            + v2 * b2f((unsigned short)g2) + v3 * b2f((unsigned short)g3);
        ay += v0 * b2f((unsigned short)(g0 >> 16)) + v1 * b2f((unsigned short)(g1 >> 16))
            + v2 * b2f((unsigned short)(g2 >> 16)) + v3 * b2f((unsigned short)(g3 >> 16));
    }
    for (; i < end; i++) {
        int c = ecol[i];
        float v = enval[i];
        unsigned int g = *(const unsigned int*)&XW[(size_t)c * 128 + d0];
        ax += v * b2f((unsigned short)g);
        ay += v * b2f((unsigned short)(g >> 16));
    }
    ax = fmaxf(ax, 0.f);
    ay = fmaxf(ay, 0.f);
    unsigned int packed = (unsigned)f2b(ax) | ((unsigned)f2b(ay) << 16);
    *(unsigned int*)&H[(size_t)r * 128 + d0] = packed;
}

// layer 2: D=64 bf16 in, lane = 1 dim; fp32 out, no activation.
__global__ __launch_bounds__(BLK) void spmm2K(const unsigned short* __restrict__ HW,
                                              const int* __restrict__ rowptr,
                                              const int* __restrict__ ecol,
                                              const float* __restrict__ enval,
                                              const float* __restrict__ dis,
                                              float* __restrict__ out, int n) {
    int wid = (blockIdx.x * BLK + threadIdx.x) >> 6;
    int lane = threadIdx.x & 63;
    if (wid >= n) return;
    int r = wid;
    float ds = dis[r];
    float acc = ds * ds * b2f(HW[(size_t)r * 64 + lane]);
    int beg = rowptr[r], end = rowptr[r + 1];
    int i = beg;
    for (; i + 4 <= end; i += 4) {
        int c0 = ecol[i], c1 = ecol[i + 1], c2 = ecol[i + 2], c3 = ecol[i + 3];
        float v0 = enval[i], v1 = enval[i + 1], v2 = enval[i + 2], v3 = enval[i + 3];
        float g0 = b2f(HW[(size_t)c0 * 64 + lane]);
        float g1 = b2f(HW[(size_t)c1 * 64 + lane]);
        float g2 = b2f(HW[(size_t)c2 * 64 + lane]);
        float g3 = b2f(HW[(size_t)c3 * 64 + lane]);
        acc += v0 * g0 + v1 * g1 + v2 * g2 + v3 * g3;
    }
    for (; i < end; i++) {
        int c = ecol[i];
        acc += enval[i] * b2f(HW[(size_t)c * 64 + lane]);
    }
    out[(size_t)r * 64 + lane] = acc;
}

// ---------------- launch ----------------

extern "C" void kernel_launch(void* const* d_in, const int* in_sizes, int n_in,
                              void* d_out, int out_size, void* d_ws, size_t ws_size,
                              hipStream_t stream) {
    const float* x = (const float*)d_in[0];
    const int* erow = (const int*)d_in[1];
    const int* ecolin = (const int*)d_in[2];
    const float* evals = (const float*)d_in[3];
    const int* emask = (const int*)d_in[4];     // bool canonicalized to int32
    const float* W0 = (const float*)d_in[5];
    const float* W1 = (const float*)d_in[6];
    float* out = (float*)d_out;

    const int n = in_sizes[0] / 128;   // 50000
    const int e = in_sizes[1];         // 600000

    char* ws = (char*)d_ws;
    size_t off = 0;
    auto alloc = [&](size_t bytes) {
        void* p = ws + off;
        off += (bytes + 255) & ~(size_t)255;
        return p;
    };
    float* degdis = (float*)alloc((size_t)n * 4);
    int* counts = (int*)alloc((size_t)n * 4);
    int* rowptr = (int*)alloc((size_t)(n + 1) * 4);
    int* bsums = (int*)alloc(1024 * 4);
    int* rankA = (int*)alloc((size_t)e * 4);
    int* ecol = (int*)alloc((size_t)e * 4);
    float* enval = (float*)alloc((size_t)e * 4);
    unsigned short* W0T = (unsigned short*)alloc(128 * 128 * 2);
    unsigned short* W1T = (unsigned short*)alloc(64 * 128 * 2);
    unsigned short* XW = (unsigned short*)alloc((size_t)n * 128 * 2);
    unsigned short* H = (unsigned short*)alloc((size_t)n * 128 * 2);
    unsigned short* HW1 = XW;  // reuse: XW dead after spmm1 (n*64 bf16 fits)

    int nbN = (n + BLK - 1) / BLK;   // 196
    int nbE = (e + BLK - 1) / BLK;   // 2344
    int nbG = (n + 63) / 64;         // 782 gemm blocks

    prepK<<<nbN, BLK, 0, stream>>>(W0, W1, W0T, W1T, degdis, counts, n);
    countK<<<nbE, BLK, 0, stream>>>(erow, evals, emask, degdis, counts, rankA, e);
    scan1K<<<nbN, BLK, 0, stream>>>(counts, rowptr, bsums, degdis, n);
    scan2K<<<1, BLK, 0, stream>>>(bsums, nbN);
    scan3K<<<nbN, BLK, 0, stream>>>(rowptr, bsums, n);
    scatterK<<<nbE, BLK, 0, stream>>>(erow, ecolin, evals, emask, degdis,
                                      rowptr, rankA, ecol, enval, e);

    mgemmK<128, false><<<nbG, BLK, 0, stream>>>(x, W0T, XW, n);
    spmm1K<<<(n + 3) / 4, BLK, 0, stream>>>(XW, rowptr, ecol, enval, degdis, H, n);
    mgemmK<64, true><<<nbG, BLK, 0, stream>>>(H, W1T, HW1, n);
    spmm2K<<<(n + 3) / 4, BLK, 0, stream>>>(HW1, rowptr, ecol, enval, degdis, out, n);
}

// Round 5
// 121.753 us; speedup vs baseline: 1.6740x; 1.0248x over previous
//
#include <hip/hip_runtime.h>
#include <hip/hip_bf16.h>

// GCN with DropEdge: out = A_norm @ (relu(A_norm @ (X@W0)) @ W1)
// A_norm = D^-1/2 (mask.A + I) D^-1/2
// N=50000, E=600000, D_IN=D_HID=128, D_OUT=64. fp32 in/out.
// bf16 MFMA GEMMs; bf16 intermediates; spmm1 fused with layer-2 GEMM
// (H tile lives only in LDS). Edge list packed (col,val) int2, consumed
// via scalar loads (readfirstlane'd row -> s_load).

#define BLK 256

typedef __attribute__((ext_vector_type(8))) short short8v;
typedef __attribute__((ext_vector_type(8))) unsigned short ushort8v;
typedef __attribute__((ext_vector_type(4))) unsigned short ushort4v;
typedef __attribute__((ext_vector_type(4))) float float4v;

__device__ inline unsigned short f2b(float f) {
    __hip_bfloat16 h = __float2bfloat16(f);
    return *reinterpret_cast<unsigned short*>(&h);
}
__device__ inline float b2f(unsigned short u) {
    unsigned int v = (unsigned int)u << 16;
    return *reinterpret_cast<float*>(&v);
}

// ---------------- prep: weight transpose->bf16 + deg/count init ----------------
__global__ __launch_bounds__(BLK) void prepK(const float* __restrict__ W0,
                                             const float* __restrict__ W1,
                                             unsigned short* __restrict__ W0T,
                                             unsigned short* __restrict__ W1T,
                                             float* deg, int* counts, int n) {
    int i = blockIdx.x * BLK + threadIdx.x;
    if (i < n) { deg[i] = 1.0f; counts[i] = 0; }
    if (i < 128 * 128) {
        int c = i >> 7, k = i & 127;
        W0T[i] = f2b(W0[k * 128 + c]);
    } else if (i < 128 * 128 + 64 * 128) {
        int j = i - 128 * 128;
        int c = j >> 7, k = j & 127;
        W1T[j] = f2b(W1[k * 64 + c]);
    }
}

// count + degree + within-row rank (atomic returns old count)
__global__ __launch_bounds__(BLK) void countK(const int* __restrict__ erow,
                                              const float* __restrict__ evals,
                                              const int* __restrict__ emask,
                                              float* deg, int* counts,
                                              int* __restrict__ rankA, int e) {
    int i = blockIdx.x * BLK + threadIdx.x;
    if (i >= e) return;
    if (!emask[i]) return;
    int r = erow[i];
    int rank = atomicAdd(&counts[r], 1);
    atomicAdd(&deg[r], evals[i]);
    rankA[i] = rank;
}

// per-block inclusive scan into rowptr[i+1] + block totals + fused d^-1/2
__global__ __launch_bounds__(BLK) void scan1K(const int* __restrict__ counts,
                                              int* __restrict__ rowptr,
                                              int* __restrict__ bsums,
                                              float* degdis, int n) {
    __shared__ int s[BLK];
    int t = threadIdx.x;
    int i = blockIdx.x * BLK + t;
    int v = (i < n) ? counts[i] : 0;
    s[t] = v;
    __syncthreads();
    for (int off = 1; off < BLK; off <<= 1) {
        int u = (t >= off) ? s[t - off] : 0;
        __syncthreads();
        s[t] += u;
        __syncthreads();
    }
    if (i < n) {
        rowptr[i + 1] = s[t];
        degdis[i] = fminf(rsqrtf(degdis[i]), 10.0f);
    }
    if (t == BLK - 1) bsums[blockIdx.x] = s[t];
}

// exclusive scan of block totals (196 <= 256)
__global__ __launch_bounds__(BLK) void scan2K(int* bsums, int nb) {
    __shared__ int s[BLK];
    int t = threadIdx.x;
    int v = (t < nb) ? bsums[t] : 0;
    s[t] = v;
    __syncthreads();
    for (int off = 1; off < BLK; off <<= 1) {
        int u = (t >= off) ? s[t - off] : 0;
        __syncthreads();
        s[t] += u;
        __syncthreads();
    }
    if (t < nb) bsums[t] = s[t] - v;
}

// edge position: end(r) = rowptr[r+1]+bsums[r>>8]; beg(r) = end(r)-counts[r]
// rank-based scatter, packed (col, valbits) int2, no atomics
__global__ __launch_bounds__(BLK) void scatterK(const int* __restrict__ erow,
                                                const int* __restrict__ ecolin,
                                                const float* __restrict__ evals,
                                                const int* __restrict__ emask,
                                                const float* __restrict__ dis,
                                                const int* __restrict__ rowptr,
                                                const int* __restrict__ counts,
                                                const int* __restrict__ bsums,
                                                const int* __restrict__ rankA,
                                                int2* __restrict__ epack, int e) {
    int i = blockIdx.x * BLK + threadIdx.x;
    if (i >= e) return;
    if (!emask[i]) return;
    int r = erow[i], c = ecolin[i];
    int endp = rowptr[r + 1] + bsums[r >> 8];
    int pos = endp - counts[r] + rankA[i];
    float nv = evals[i] * dis[r] * dis[c];
    epack[pos] = make_int2(c, __float_as_int(nv));
}

// ---------------- MFMA GEMM1: XW[M,128](bf16) = X[M,128](fp32) @ W0 ------------
// W0T = W0^T bf16 [128][128]. Block: 4 waves, 64 rows.
// LDS XOR swizzle (short-units: idx ^ ((row&7)<<3)) -> 2-way banks on b128 reads.
__global__ __launch_bounds__(BLK) void mgemm1K(const float* __restrict__ A,
                                               const unsigned short* __restrict__ WT,
                                               unsigned short* __restrict__ C, int M) {
    constexpr int NC = 128, NT = NC / 16;
    __shared__ __align__(16) unsigned short sA[64 * 128];
    __shared__ __align__(16) unsigned short sB[NC * 128];
    int t = threadIdx.x;
    int row0 = blockIdx.x * 64;

    for (int ch = t; ch < NC * 16; ch += BLK) {
        int row = ch >> 4, c16 = ch & 15;
        int dst = row * 128 + ((c16 * 8) ^ ((row & 7) << 3));
        *(ushort8v*)&sB[dst] = *(const ushort8v*)&WT[row * 128 + c16 * 8];
    }
    for (int q = t; q < 64 * 32; q += BLK) {
        int row = q >> 5, c4 = q & 31;
        int rg = row0 + row;
        float4 v = make_float4(0.f, 0.f, 0.f, 0.f);
        if (rg < M) v = *(const float4*)&A[(size_t)rg * 128 + c4 * 4];
        ushort4v b = {f2b(v.x), f2b(v.y), f2b(v.z), f2b(v.w)};
        int dst = row * 128 + ((c4 * 4) ^ ((row & 7) << 3));
        *(ushort4v*)&sA[dst] = b;
    }
    __syncthreads();

    int w = t >> 6, l = t & 63;
    int arow = w * 16 + (l & 15);
    int kgrp = l >> 4;
    int bcol = l & 15;
    float4v acc[NT];
#pragma unroll
    for (int nt = 0; nt < NT; nt++) acc[nt] = {0.f, 0.f, 0.f, 0.f};
#pragma unroll
    for (int ks = 0; ks < 4; ks++) {
        int koff = ks * 32 + kgrp * 8;
        short8v av = *(short8v*)&sA[arow * 128 + (koff ^ ((arow & 7) << 3))];
#pragma unroll
        for (int nt = 0; nt < NT; nt++) {
            int brow = nt * 16 + bcol;
            short8v bv = *(short8v*)&sB[brow * 128 + (koff ^ ((brow & 7) << 3))];
            acc[nt] = __builtin_amdgcn_mfma_f32_16x16x32_bf16(av, bv, acc[nt], 0, 0, 0);
        }
    }
    int crow0 = row0 + w * 16 + kgrp * 4;
#pragma unroll
    for (int nt = 0; nt < NT; nt++) {
#pragma unroll
        for (int j = 0; j < 4; j++) {
            int r = crow0 + j;
            if (r < M) C[(size_t)r * NC + nt * 16 + bcol] = f2b(acc[nt][j]);
        }
    }
}

// ------------- fused: H-tile = relu(A_norm @ XW) in LDS; HW1 = H @ W1 ----------
// Block: 64 rows, 4 waves. Phase 1: wave w computes rows w*16..+16 of the SpMM
// (lane = 2 dims), writes bf16 into swizzled LDS. Phase 2: mgemm NC=64.
__global__ __launch_bounds__(BLK) void fuse1K(const unsigned short* __restrict__ XW,
                                              const int* __restrict__ rowptr,
                                              const int* __restrict__ counts,
                                              const int* __restrict__ bsums,
                                              const int2* __restrict__ epack,
                                              const float* __restrict__ dis,
                                              const unsigned short* __restrict__ W1T,
                                              unsigned short* __restrict__ HW1, int n) {
    constexpr int NC = 64, NT = NC / 16;
    __shared__ __align__(16) unsigned short sA[64 * 128];
    __shared__ __align__(16) unsigned short sB[NC * 128];
    int t = threadIdx.x;
    int w = t >> 6, l = t & 63;
    int row0 = blockIdx.x * 64;

    for (int ch = t; ch < NC * 16; ch += BLK) {
        int row = ch >> 4, c16 = ch & 15;
        int dst = row * 128 + ((c16 * 8) ^ ((row & 7) << 3));
        *(ushort8v*)&sB[dst] = *(const ushort8v*)&W1T[row * 128 + c16 * 8];
    }

    // phase 1: SpMM rows into LDS
    int d0 = l * 2;
    for (int rr = 0; rr < 16; rr++) {
        int lr = w * 16 + rr;
        int r = __builtin_amdgcn_readfirstlane(row0 + lr);
        float ax = 0.f, ay = 0.f;
        if (r < n) {
            float ds = dis[r];
            unsigned int sv = *(const unsigned int*)&XW[(size_t)r * 128 + d0];
            ax = ds * ds * b2f((unsigned short)sv);
            ay = ds * ds * b2f((unsigned short)(sv >> 16));
            int endp = rowptr[r + 1] + bsums[r >> 8];
            int beg = endp - counts[r];
            int i = beg;
            for (; i + 4 <= endp; i += 4) {
                int2 e0 = epack[i], e1 = epack[i + 1], e2 = epack[i + 2], e3 = epack[i + 3];
                unsigned int g0 = *(const unsigned int*)&XW[(size_t)e0.x * 128 + d0];
                unsigned int g1 = *(const unsigned int*)&XW[(size_t)e1.x * 128 + d0];
                unsigned int g2 = *(const unsigned int*)&XW[(size_t)e2.x * 128 + d0];
                unsigned int g3 = *(const unsigned int*)&XW[(size_t)e3.x * 128 + d0];
                float v0 = __int_as_float(e0.y), v1 = __int_as_float(e1.y);
                float v2 = __int_as_float(e2.y), v3 = __int_as_float(e3.y);
                ax += v0 * b2f((unsigned short)g0) + v1 * b2f((unsigned short)g1)
                    + v2 * b2f((unsigned short)g2) + v3 * b2f((unsigned short)g3);
                ay += v0 * b2f((unsigned short)(g0 >> 16)) + v1 * b2f((unsigned short)(g1 >> 16))
                    + v2 * b2f((unsigned short)(g2 >> 16)) + v3 * b2f((unsigned short)(g3 >> 16));
            }
            for (; i < endp; i++) {
                int2 ep = epack[i];
                unsigned int g = *(const unsigned int*)&XW[(size_t)ep.x * 128 + d0];
                float v = __int_as_float(ep.y);
                ax += v * b2f((unsigned short)g);
                ay += v * b2f((unsigned short)(g >> 16));
            }
            ax = fmaxf(ax, 0.f);
            ay = fmaxf(ay, 0.f);
        }
        unsigned int packed = (unsigned)f2b(ax) | ((unsigned)f2b(ay) << 16);
        *(unsigned int*)&sA[lr * 128 + (d0 ^ ((lr & 7) << 3))] = packed;
    }
    __syncthreads();

    // phase 2: HW1 tile = sA @ W1
    int arow = w * 16 + (l & 15);
    int kgrp = l >> 4;
    int bcol = l & 15;
    float4v acc[NT];
#pragma unroll
    for (int nt = 0; nt < NT; nt++) acc[nt] = {0.f, 0.f, 0.f, 0.f};
#pragma unroll
    for (int ks = 0; ks < 4; ks++) {
        int koff = ks * 32 + kgrp * 8;
        short8v av = *(short8v*)&sA[arow * 128 + (koff ^ ((arow & 7) << 3))];
#pragma unroll
        for (int nt = 0; nt < NT; nt++) {
            int brow = nt * 16 + bcol;
            short8v bv = *(short8v*)&sB[brow * 128 + (koff ^ ((brow & 7) << 3))];
            acc[nt] = __builtin_amdgcn_mfma_f32_16x16x32_bf16(av, bv, acc[nt], 0, 0, 0);
        }
    }
    int crow0 = row0 + w * 16 + kgrp * 4;
#pragma unroll
    for (int nt = 0; nt < NT; nt++) {
#pragma unroll
        for (int j = 0; j < 4; j++) {
            int r = crow0 + j;
            if (r < n) HW1[(size_t)r * NC + nt * 16 + bcol] = f2b(acc[nt][j]);
        }
    }
}

// ---------------- layer-2 SpMM: out = A_norm @ HW1 (D=64) ---------------------
__global__ __launch_bounds__(BLK) void spmm2K(const unsigned short* __restrict__ HW,
                                              const int* __restrict__ rowptr,
                                              const int* __restrict__ counts,
                                              const int* __restrict__ bsums,
                                              const int2* __restrict__ epack,
                                              const float* __restrict__ dis,
                                              float* __restrict__ out, int n) {
    int wid = (blockIdx.x * BLK + threadIdx.x) >> 6;
    int lane = threadIdx.x & 63;
    if (wid >= n) return;
    int r = __builtin_amdgcn_readfirstlane(wid);
    float ds = dis[r];
    float acc = ds * ds * b2f(HW[(size_t)r * 64 + lane]);
    int endp = rowptr[r + 1] + bsums[r >> 8];
    int beg = endp - counts[r];
    int i = beg;
    for (; i + 4 <= endp; i += 4) {
        int2 e0 = epack[i], e1 = epack[i + 1], e2 = epack[i + 2], e3 = epack[i + 3];
        float g0 = b2f(HW[(size_t)e0.x * 64 + lane]);
        float g1 = b2f(HW[(size_t)e1.x * 64 + lane]);
        float g2 = b2f(HW[(size_t)e2.x * 64 + lane]);
        float g3 = b2f(HW[(size_t)e3.x * 64 + lane]);
        acc += __int_as_float(e0.y) * g0 + __int_as_float(e1.y) * g1
             + __int_as_float(e2.y) * g2 + __int_as_float(e3.y) * g3;
    }
    for (; i < endp; i++) {
        int2 ep = epack[i];
        acc += __int_as_float(ep.y) * b2f(HW[(size_t)ep.x * 64 + lane]);
    }
    out[(size_t)r * 64 + lane] = acc;
}

// ---------------- launch ----------------

extern "C" void kernel_launch(void* const* d_in, const int* in_sizes, int n_in,
                              void* d_out, int out_size, void* d_ws, size_t ws_size,
                              hipStream_t stream) {
    const float* x = (const float*)d_in[0];
    const int* erow = (const int*)d_in[1];
    const int* ecolin = (const int*)d_in[2];
    const float* evals = (const float*)d_in[3];
    const int* emask = (const int*)d_in[4];     // bool canonicalized to int32
    const float* W0 = (const float*)d_in[5];
    const float* W1 = (const float*)d_in[6];
    float* out = (float*)d_out;

    const int n = in_sizes[0] / 128;   // 50000
    const int e = in_sizes[1];         // 600000

    char* ws = (char*)d_ws;
    size_t off = 0;
    auto alloc = [&](size_t bytes) {
        void* p = ws + off;
        off += (bytes + 255) & ~(size_t)255;
        return p;
    };
    float* degdis = (float*)alloc((size_t)n * 4);
    int* counts = (int*)alloc((size_t)n * 4);
    int* rowptr = (int*)alloc((size_t)(n + 1) * 4);
    int* bsums = (int*)alloc(1024 * 4);
    int* rankA = (int*)alloc((size_t)e * 4);
    int2* epack = (int2*)alloc((size_t)e * 8);
    unsigned short* W0T = (unsigned short*)alloc(128 * 128 * 2);
    unsigned short* W1T = (unsigned short*)alloc(64 * 128 * 2);
    unsigned short* XW = (unsigned short*)alloc((size_t)n * 128 * 2);
    unsigned short* HW1 = (unsigned short*)alloc((size_t)n * 64 * 2);

    int nbN = (n + BLK - 1) / BLK;   // 196
    int nbE = (e + BLK - 1) / BLK;   // 2344
    int nbG = (n + 63) / 64;         // 782

    prepK<<<nbN, BLK, 0, stream>>>(W0, W1, W0T, W1T, degdis, counts, n);
    countK<<<nbE, BLK, 0, stream>>>(erow, evals, emask, degdis, counts, rankA, e);
    scan1K<<<nbN, BLK, 0, stream>>>(counts, rowptr, bsums, degdis, n);
    scan2K<<<1, BLK, 0, stream>>>(bsums, nbN);
    scatterK<<<nbE, BLK, 0, stream>>>(erow, ecolin, evals, emask, degdis,
                                      rowptr, counts, bsums, rankA, epack, e);

    mgemm1K<<<nbG, BLK, 0, stream>>>(x, W0T, XW, n);
    fuse1K<<<nbG, BLK, 0, stream>>>(XW, rowptr, counts, bsums, epack, degdis,
                                    W1T, HW1, n);
    spmm2K<<<(n + 3) / 4, BLK, 0, stream>>>(HW1, rowptr, counts, bsums, epack,
                                            degdis, out, n);
}